// Round 5
// baseline (217.890 us; speedup 1.0000x reference)
//
#include <hip/hip_runtime.h>
#include <math.h>

typedef __attribute__((ext_vector_type(8))) short short8;   // 8 bf16 (4 VGPRs)
typedef __attribute__((ext_vector_type(4))) float f32x4;    // MFMA accumulator

constexpr int kD  = 2048;
constexpr int kE  = 64;
constexpr int kM  = 32;          // tokens per block -> 512 blocks -> 2/CU
constexpr int kBK = 64;          // K per staging iteration
constexpr int kIt = kD / kBK;    // 32
// A-limb LDS, fragment order per 16-token tile: addr = (16o+r)*48 + o*16 + j*2
constexpr int kTS  = 3136;       // per-16-token-tile stride bytes (o-padded)
constexpr int kCS2 = 2 * kTS;    // per-32-K c-group stride: 2 token-tiles
constexpr int kBuf = 2 * kCS2;   // 12544 B per it-buffer (2 c-groups)

// p limbs pre-converted to MFMA B-fragment order:
// g_B[plane][e0=e>>4][gc=k>>5][L=16*((k>>3)&3)+(e&15)][j=k&7]   (ushorts)
constexpr int kPlaneU = 4 * 64 * 512;   // 131072 ushorts per plane
__device__ unsigned short g_B[3 * kPlaneU];   // 786 KB

// 3-limb truncated bf16 split: v = h + m + l + O(2^-24 |v|)
__device__ __forceinline__ void split3(float v, unsigned& h, unsigned& m, unsigned& l) {
  unsigned u = __float_as_uint(v);
  h = u & 0xFFFF0000u;
  float r1 = v - __uint_as_float(h);
  m = __float_as_uint(r1) & 0xFFFF0000u;
  float r2 = r1 - __uint_as_float(m);
  l = __float_as_uint(r2);
}

// pack limbs of two consecutive elements into one dword per plane
__device__ __forceinline__ void pack2(float e0, float e1,
                                      unsigned& dh, unsigned& dm, unsigned& dl) {
  unsigned h0, m0, l0, h1, m1, l1;
  split3(e0, h0, m0, l0);
  split3(e1, h1, m1, l1);
  dh = (h0 >> 16) | h1;
  dm = (m0 >> 16) | m1;
  dl = (l0 >> 16) | (l1 & 0xFFFF0000u);
}

// ---------------------------------------------------------------------------
// Prep: S_e, inv_norm_e into ws; p 3-limb bf16 into g_B in B-fragment order.
// ---------------------------------------------------------------------------
__global__ __launch_bounds__(256) void proto_prep(const float* __restrict__ p,
                                                  float* __restrict__ ws) {
  const int e = blockIdx.x, t = threadIdx.x;
  const float* row = p + (size_t)e * kD;
  float4 v0 = *(const float4*)(row + 8 * t);
  float4 v1 = *(const float4*)(row + 8 * t + 4);

  unsigned dh[4], dm[4], dl[4];
  pack2(v0.x, v0.y, dh[0], dm[0], dl[0]);
  pack2(v0.z, v0.w, dh[1], dm[1], dl[1]);
  pack2(v1.x, v1.y, dh[2], dm[2], dl[2]);
  pack2(v1.z, v1.w, dh[3], dm[3], dl[3]);
  const int gc = t >> 2, o = t & 3;
  size_t base = (size_t)((e >> 4) * 64 + gc) * 512 + (16 * o + (e & 15)) * 8;
  *(uint4*)&g_B[base]               = make_uint4(dh[0], dh[1], dh[2], dh[3]);
  *(uint4*)&g_B[kPlaneU + base]     = make_uint4(dm[0], dm[1], dm[2], dm[3]);
  *(uint4*)&g_B[2 * kPlaneU + base] = make_uint4(dl[0], dl[1], dl[2], dl[3]);

  float s = (v0.x + v0.y) + (v0.z + v0.w) + (v1.x + v1.y) + (v1.z + v1.w);
  float q = v0.x*v0.x + v0.y*v0.y + v0.z*v0.z + v0.w*v0.w
          + v1.x*v1.x + v1.y*v1.y + v1.z*v1.z + v1.w*v1.w;
  #pragma unroll
  for (int off = 32; off >= 1; off >>= 1) {
    s += __shfl_xor(s, off, 64);
    q += __shfl_xor(q, off, 64);
  }
  __shared__ float as[4], aq[4];
  if ((t & 63) == 0) { as[t >> 6] = s; aq[t >> 6] = q; }
  __syncthreads();
  if (t == 0) {
    float S = (as[0] + as[1]) + (as[2] + as[3]);
    float Q = (aq[0] + aq[1]) + (aq[2] + aq[3]);
    ws[e]      = S;
    ws[kE + e] = 1.f / fmaxf(sqrtf(Q), 1e-8f);
  }
}

// ---------------------------------------------------------------------------
// Main: 32 tokens/block, 8 waves (512 thr) = expert-quad x token-half split,
// one 16x16 tile per wave. 2 blocks/CU x 8 waves = 16 waves/CU = 4/SIMD.
// kBK=64 double-buffered LDS (34 KB/block), VGPR-trimmed pipelines
// (B depth-1, x depth-2). Dot accumulation order identical to the verified
// kernel (gc = 0..63 in order, same 6-limb MFMA sequence).
// ---------------------------------------------------------------------------
__global__ __launch_bounds__(512, 4) void router_main(
    const float* __restrict__ x, const float* __restrict__ ws,
    float* __restrict__ out_w, float* __restrict__ out_i) {
  __shared__ __align__(16) unsigned char sA[2 * kBuf];  // 25088 B
  __shared__ float sLogit[kM * 68];                     //  8704 B
  __shared__ float sStats[kM][2];                       //   256 B

  const int t    = threadIdx.x;     // 0..511
  const int w    = t >> 6;          // wave 0..7
  const int L    = t & 63;
  const int eg   = w & 3;           // expert group: experts [16*eg, 16*eg+16)
  const int th   = w >> 2;          // token half:  tokens  [16*th, 16*th+16)
  const int ln15 = L & 15;
  const int q    = L >> 4;
  const int tok0 = blockIdx.x * kM;
  const float* xg = x + (size_t)tok0 * kD;

  // staging geometry: thread t stages token mS = t>>4, k-cols colS..colS+3
  const int mS   = t >> 4;          // 0..31
  const int colS = (t & 15) * 4;    // 0..60
  const int cS   = colS >> 5;       // c-group 0/1
  const int oS   = (colS >> 3) & 3;
  const int jS   = colS & 7;        // 0 or 4
  const int woff = cS * kCS2 + (mS >> 4) * kTS + (mS & 15) * 48
                 + (16 * oS) * 48 + oS * 16 + jS * 2;

  f32x4 acc = (f32x4){0.f, 0.f, 0.f, 0.f};
  float sx = 0.f, sxx = 0.f;

  auto stage = [&](const float4 v, unsigned char* wb) {
    unsigned dh0, dm0, dl0, dh1, dm1, dl1;
    pack2(v.x, v.y, dh0, dm0, dl0);
    pack2(v.z, v.w, dh1, dm1, dl1);
    sx += (v.x + v.y) + (v.z + v.w);
    sxx = fmaf(v.x, v.x, fmaf(v.y, v.y, fmaf(v.z, v.z, fmaf(v.w, v.w, sxx))));
    unsigned char* dst = wb + woff;
    *(uint2*)(dst)      = make_uint2(dh0, dh1);   // plane h
    *(uint2*)(dst + 16) = make_uint2(dm0, dm1);   // plane m
    *(uint2*)(dst + 32) = make_uint2(dl0, dl1);   // plane l
  };

  // ---- prologue: stage chunk 0 into buf0, prefetch chunk 1, preload B(0)
  float4 pfA, pfB;
  pfA = *(const float4*)(xg + (size_t)mS * kD + colS);
  stage(pfA, sA);
  pfA = *(const float4*)(xg + (size_t)mS * kD + kBK + colS);
  pfB = pfA;

  short8 Bch, Bcm, Bcl;
  {
    const size_t bo = (size_t)(eg * 64 + 0) * 512 + L * 8;
    Bch = *(const short8*)&g_B[bo];
    Bcm = *(const short8*)&g_B[kPlaneU + bo];
    Bcl = *(const short8*)&g_B[2 * kPlaneU + bo];
  }
  __syncthreads();

  const int aoff = th * kTS + L * 48 + (L >> 4) * 16;

  for (int it = 0; it < kIt; ++it) {
    unsigned char* rb = sA + (it & 1) * kBuf;
    unsigned char* wb = sA + ((it & 1) ^ 1) * kBuf;

    // x prefetch, 2 iterations ahead
    if (it + 2 < kIt)
      pfB = *(const float4*)(xg + (size_t)mS * kD + (it + 2) * kBK + colS);

    // A fragments, c-group 0
    const unsigned char* ra0 = rb + aoff;
    short8 Ah0 = *(const short8*)(ra0);
    short8 Am0 = *(const short8*)(ra0 + 16);
    short8 Al0 = *(const short8*)(ra0 + 32);

    // B for c-step 1 (depth-1 prefetch)
    const int gc1 = it * 2 + 1;
    const size_t bo1 = (size_t)(eg * 64 + gc1) * 512 + L * 8;
    short8 Bnh = *(const short8*)&g_B[bo1];
    short8 Bnm = *(const short8*)&g_B[kPlaneU + bo1];
    short8 Bnl = *(const short8*)&g_B[2 * kPlaneU + bo1];

    // stage next iteration's chunk into the other buffer (drains under MFMA)
    if (it + 1 < kIt)
      stage(pfA, wb);

    // A fragments, c-group 1
    const unsigned char* ra1 = rb + kCS2 + aoff;
    short8 Ah1 = *(const short8*)(ra1);
    short8 Am1 = *(const short8*)(ra1 + 16);
    short8 Al1 = *(const short8*)(ra1 + 32);

    // c-step 0: 6 limb products hh, hm, mh, mm, hl, lh (order preserved)
    __builtin_amdgcn_s_setprio(1);
    acc = __builtin_amdgcn_mfma_f32_16x16x32_bf16(Ah0, Bch, acc, 0, 0, 0);
    acc = __builtin_amdgcn_mfma_f32_16x16x32_bf16(Ah0, Bcm, acc, 0, 0, 0);
    acc = __builtin_amdgcn_mfma_f32_16x16x32_bf16(Am0, Bch, acc, 0, 0, 0);
    acc = __builtin_amdgcn_mfma_f32_16x16x32_bf16(Am0, Bcm, acc, 0, 0, 0);
    acc = __builtin_amdgcn_mfma_f32_16x16x32_bf16(Ah0, Bcl, acc, 0, 0, 0);
    acc = __builtin_amdgcn_mfma_f32_16x16x32_bf16(Al0, Bch, acc, 0, 0, 0);
    __builtin_amdgcn_s_setprio(0);

    // B for next iteration's c-step 0 (wraps harmlessly at the end)
    const int gc2 = (it * 2 + 2) & 63;
    const size_t bo2 = (size_t)(eg * 64 + gc2) * 512 + L * 8;
    short8 Bfh = *(const short8*)&g_B[bo2];
    short8 Bfm = *(const short8*)&g_B[kPlaneU + bo2];
    short8 Bfl = *(const short8*)&g_B[2 * kPlaneU + bo2];

    // c-step 1
    __builtin_amdgcn_s_setprio(1);
    acc = __builtin_amdgcn_mfma_f32_16x16x32_bf16(Ah1, Bnh, acc, 0, 0, 0);
    acc = __builtin_amdgcn_mfma_f32_16x16x32_bf16(Ah1, Bnm, acc, 0, 0, 0);
    acc = __builtin_amdgcn_mfma_f32_16x16x32_bf16(Am1, Bnh, acc, 0, 0, 0);
    acc = __builtin_amdgcn_mfma_f32_16x16x32_bf16(Am1, Bnm, acc, 0, 0, 0);
    acc = __builtin_amdgcn_mfma_f32_16x16x32_bf16(Ah1, Bnl, acc, 0, 0, 0);
    acc = __builtin_amdgcn_mfma_f32_16x16x32_bf16(Al1, Bnh, acc, 0, 0, 0);
    __builtin_amdgcn_s_setprio(0);

    Bch = Bfh; Bcm = Bfm; Bcl = Bfl;

    __syncthreads();
    if (it + 2 < kIt) pfA = pfB;
  }

  // LN stats: token = 4w + (L>>4); reduce across the 16 lanes sharing it
  {
    float a = sx, b = sxx;
    #pragma unroll
    for (int off = 8; off >= 1; off >>= 1) {
      a += __shfl_xor(a, off, 64);
      b += __shfl_xor(b, off, 64);
    }
    if ((L & 15) == 0) {
      int m = 4 * w + (L >> 4);
      sStats[m][0] = a;
      sStats[m][1] = b;
    }
  }

  // raw dots -> LDS  (row = token, col = expert)
  #pragma unroll
  for (int i = 0; i < 4; ++i)
    sLogit[(th * 16 + q * 4 + i) * 68 + eg * 16 + ln15] = acc[i];
  __syncthreads();

  // epilogue: wave w -> tokens [4w, 4w+4), lane = expert
  const float Se  = ws[L];
  const float inv = ws[kE + L];
  #pragma unroll
  for (int tl = 0; tl < 4; ++tl) {
    int tk = w * 4 + tl;
    float mu   = sStats[tk][0] * (1.f / kD);
    float var  = sStats[tk][1] * (1.f / kD) - mu * mu;
    float rstd = rsqrtf(var + 1e-5f);
    float logit = (sLogit[tk * 68 + L] - mu * Se) * rstd * inv * 0.125f;

    float v1 = logit; int i1 = L;
    #pragma unroll
    for (int off = 32; off >= 1; off >>= 1) {
      float ov = __shfl_xor(v1, off, 64);
      int   oi = __shfl_xor(i1, off, 64);
      if (ov > v1 || (ov == v1 && oi < i1)) { v1 = ov; i1 = oi; }
    }
    float ml = (L == i1) ? -3.402823466e38f : logit;
    float v2 = ml; int i2 = L;
    #pragma unroll
    for (int off = 32; off >= 1; off >>= 1) {
      float ov = __shfl_xor(v2, off, 64);
      int   oi = __shfl_xor(i2, off, 64);
      if (ov > v2 || (ov == v2 && oi < i2)) { v2 = ov; i2 = oi; }
    }
    if (L == 0) {
      int tg = tok0 + tk;
      float er = expf(v2 - v1);
      float r  = 1.f / (1.f + er);
      out_w[2 * tg]     = r;
      out_w[2 * tg + 1] = er * r;
      out_i[2 * tg]     = (float)i1;   // harness reads whole buffer as f32
      out_i[2 * tg + 1] = (float)i2;
    }
  }
}

extern "C" void kernel_launch(void* const* d_in, const int* in_sizes, int n_in,
                              void* d_out, int out_size, void* d_ws, size_t ws_size,
                              hipStream_t stream) {
  const float* x = (const float*)d_in[0];   // [4,4096,2048] fp32
  const float* p = (const float*)d_in[1];   // [64,2048] fp32
  float* ws = (float*)d_ws;                 // 128 floats
  const int T = in_sizes[0] / kD;           // 16384 tokens
  float* out_w = (float*)d_out;
  float* out_i = (float*)d_out + (size_t)T * 2;

  proto_prep<<<kE, 256, 0, stream>>>(p, ws);
  router_main<<<T / kM, 512, 0, stream>>>(x, ws, out_w, out_i);
}

// Round 6
// 207.149 us; speedup vs baseline: 1.0518x; 1.0518x over previous
//
#include <hip/hip_runtime.h>
#include <math.h>

typedef __attribute__((ext_vector_type(8)))  short short8;   // 8 bf16 (4 VGPRs)
typedef __attribute__((ext_vector_type(16))) float f32x16;   // 32x32 MFMA acc

constexpr int kD  = 2048;
constexpr int kE  = 64;
constexpr int kM  = 32;          // tokens per block -> 512 blocks -> 2/CU
constexpr int kBK = 128;         // K per staging iteration (4 gc)
constexpr int kIt = kD / kBK;    // 16

// A-limb LDS layout per K=32 chunk (gc): [plane][octet(4)][row(32) * 16B]
// fragment reads are contiguous 1KB (conflict-free); kGS bank-rotates chunks.
constexpr int kOS  = 544;            // octet stride (512 data + 32 pad)
constexpr int kPS  = 4 * kOS;        // 2176  plane stride
constexpr int kGS  = 3 * kPS + 16;   // 6544  gc stride (+16 rotates banks)
constexpr int kBuf = 4 * kGS;        // 26176 per staging buffer (4 gc)

// p limbs in 32-expert B-fragment order:
// g_B[plane][eg=e>>5][gc=k>>5][kh=(k>>4)&1][lane=(e&31)|(((k>>3)&1)<<5)][j=k&7]
constexpr int kPlaneU = 2 * 64 * 2 * 64 * 8;  // 131072 ushorts per plane
__device__ unsigned short g_B[3 * kPlaneU];   // 786 KB

// 3-limb truncated bf16 split: v = h + m + l + O(2^-24 |v|)
__device__ __forceinline__ void split3(float v, unsigned& h, unsigned& m, unsigned& l) {
  unsigned u = __float_as_uint(v);
  h = u & 0xFFFF0000u;
  float r1 = v - __uint_as_float(h);
  m = __float_as_uint(r1) & 0xFFFF0000u;
  float r2 = r1 - __uint_as_float(m);
  l = __float_as_uint(r2);
}

// pack limbs of two consecutive elements into one dword per plane
__device__ __forceinline__ void pack2(float e0, float e1,
                                      unsigned& dh, unsigned& dm, unsigned& dl) {
  unsigned h0, m0, l0, h1, m1, l1;
  split3(e0, h0, m0, l0);
  split3(e1, h1, m1, l1);
  dh = (h0 >> 16) | h1;
  dm = (m0 >> 16) | m1;
  dl = (l0 >> 16) | (l1 & 0xFFFF0000u);
}

// ---------------------------------------------------------------------------
// Prep: S_e, inv_norm_e into ws; p 3-limb bf16 into g_B in 32-wide B-fragment
// order for mfma_f32_32x32x16_bf16 (lane l: e = 32*eg + (l&31), k = 8*(l>>5)+j).
// ---------------------------------------------------------------------------
__global__ __launch_bounds__(256) void proto_prep(const float* __restrict__ p,
                                                  float* __restrict__ ws) {
  const int e = blockIdx.x, t = threadIdx.x;
  const float* row = p + (size_t)e * kD;
  float4 v0 = *(const float4*)(row + 8 * t);
  float4 v1 = *(const float4*)(row + 8 * t + 4);

  unsigned dh[4], dm[4], dl[4];
  pack2(v0.x, v0.y, dh[0], dm[0], dl[0]);
  pack2(v0.z, v0.w, dh[1], dm[1], dl[1]);
  pack2(v1.x, v1.y, dh[2], dm[2], dl[2]);
  pack2(v1.z, v1.w, dh[3], dm[3], dl[3]);
  // thread t owns k = 8t .. 8t+7
  const int gc = t >> 2;             // k>>5
  const int kh = (t >> 1) & 1;       // (k>>4)&1
  const int lb = t & 1;              // (k>>3)&1
  size_t base = ((((size_t)(e >> 5) * 64 + gc) * 2 + kh) * 64
                 + ((e & 31) | (lb << 5))) * 8;
  *(uint4*)&g_B[base]               = make_uint4(dh[0], dh[1], dh[2], dh[3]);
  *(uint4*)&g_B[kPlaneU + base]     = make_uint4(dm[0], dm[1], dm[2], dm[3]);
  *(uint4*)&g_B[2 * kPlaneU + base] = make_uint4(dl[0], dl[1], dl[2], dl[3]);

  float s = (v0.x + v0.y) + (v0.z + v0.w) + (v1.x + v1.y) + (v1.z + v1.w);
  float q = v0.x*v0.x + v0.y*v0.y + v0.z*v0.z + v0.w*v0.w
          + v1.x*v1.x + v1.y*v1.y + v1.z*v1.z + v1.w*v1.w;
  #pragma unroll
  for (int off = 32; off >= 1; off >>= 1) {
    s += __shfl_xor(s, off, 64);
    q += __shfl_xor(q, off, 64);
  }
  __shared__ float as[4], aq[4];
  if ((t & 63) == 0) { as[t >> 6] = s; aq[t >> 6] = q; }
  __syncthreads();
  if (t == 0) {
    float S = (as[0] + as[1]) + (as[2] + as[3]);
    float Q = (aq[0] + aq[1]) + (aq[2] + aq[3]);
    ws[e]      = S;
    ws[kE + e] = 1.f / fmaxf(sqrtf(Q), 1e-8f);
  }
}

// ---------------------------------------------------------------------------
// Main: 32 tokens/block, 256 thr, 4 waves = (expert-half eg) x (K-parity kp).
// Each wave: one 32x32 tile via mfma_f32_32x32x16_bf16 over its half of K.
// Two independent acc chains (kh0/kh1) summed at the end; K-parity partials
// summed through LDS. A LDS bytes halved vs 16x16 layout; conflict-free
// fragment reads. Same 6-limb product set, same per-limb order.
// ---------------------------------------------------------------------------
__global__ __launch_bounds__(256, 2) void router_main(
    const float* __restrict__ x, const float* __restrict__ ws,
    float* __restrict__ out_w, float* __restrict__ out_i) {
  __shared__ __align__(16) unsigned char sA[2 * kBuf];  // 52352 B
  __shared__ float sLogit[2 * kM * 68];                 // 17408 B (kp planes)
  __shared__ float sStats[kM][2];                       //   256 B

  const int t    = threadIdx.x;     // 0..255
  const int w    = t >> 6;          // wave 0..3
  const int L    = t & 63;
  const int eg   = w & 1;           // experts [32*eg, 32*eg+32)
  const int kp   = w >> 1;          // K parity: gc % 2 == kp
  const int tok0 = blockIdx.x * kM;
  const float* xg = x + (size_t)tok0 * kD;

  // staging geometry: slice jj stages token mB + 8*jj, k-cols kc..kc+3
  const int mB = t >> 5;            // 0..7
  const int kc = (t & 31) * 4;      // 0..124
  const int gcS = kc >> 5;          // gc-local 0..3
  const int oS  = (kc >> 3) & 3;    // octet
  const int jS  = kc & 7;           // 0 or 4
  const int wOff = gcS * kGS + oS * kOS + jS * 2;   // + m*16 + plane*kPS

  f32x16 accA = {0.f}, accB = {0.f};
  #pragma unroll
  for (int i = 0; i < 16; ++i) { accA[i] = 0.f; accB[i] = 0.f; }
  float sx[4]  = {0.f, 0.f, 0.f, 0.f};
  float sxx[4] = {0.f, 0.f, 0.f, 0.f};

  auto stage = [&](const float4 v, float& sxr, float& sxxr, int m, unsigned char* wb) {
    unsigned dh0, dm0, dl0, dh1, dm1, dl1;
    pack2(v.x, v.y, dh0, dm0, dl0);
    pack2(v.z, v.w, dh1, dm1, dl1);
    sxr += (v.x + v.y) + (v.z + v.w);
    sxxr = fmaf(v.x, v.x, fmaf(v.y, v.y, fmaf(v.z, v.z, fmaf(v.w, v.w, sxxr))));
    unsigned char* dst = wb + wOff + m * 16;
    *(uint2*)(dst)           = make_uint2(dh0, dh1);   // plane h
    *(uint2*)(dst + kPS)     = make_uint2(dm0, dm1);   // plane m
    *(uint2*)(dst + 2 * kPS) = make_uint2(dl0, dl1);   // plane l
  };

  // B fragment address for global gc g, k-half kh
  auto bIdx = [&](int g, int kh) -> size_t {
    return ((((size_t)eg * 64 + g) * 2 + kh) * 64 + L) * 8;
  };

  // ---- prologue: stage chunk 0, prefetch chunk 1, preload B(cluster g=kp)
  float4 pfA[4], pfB[4];
  #pragma unroll
  for (int jj = 0; jj < 4; ++jj)
    pfA[jj] = *(const float4*)(xg + (size_t)(mB + 8 * jj) * kD + kc);
  #pragma unroll
  for (int jj = 0; jj < 4; ++jj)
    stage(pfA[jj], sx[jj], sxx[jj], mB + 8 * jj, sA);
  #pragma unroll
  for (int jj = 0; jj < 4; ++jj)
    pfA[jj] = *(const float4*)(xg + (size_t)(mB + 8 * jj) * kD + kBK + kc);
  #pragma unroll
  for (int jj = 0; jj < 4; ++jj) pfB[jj] = pfA[jj];

  short8 BcH0, BcM0, BcL0, BcH1, BcM1, BcL1;   // current cluster B
  {
    size_t b0 = bIdx(kp, 0), b1 = bIdx(kp, 1);
    BcH0 = *(const short8*)&g_B[b0];
    BcM0 = *(const short8*)&g_B[kPlaneU + b0];
    BcL0 = *(const short8*)&g_B[2 * kPlaneU + b0];
    BcH1 = *(const short8*)&g_B[b1];
    BcM1 = *(const short8*)&g_B[kPlaneU + b1];
    BcL1 = *(const short8*)&g_B[2 * kPlaneU + b1];
  }
  __syncthreads();

  // A fragment lane offset: row = L&31, octet = 2*kh + (L>>5)
  const int aRow = (L & 31) * 16;
  const int aOct = (L >> 5) * kOS;

  for (int it = 0; it < kIt; ++it) {
    unsigned char* rb = sA + (it & 1) * kBuf;
    unsigned char* wb = sA + ((it & 1) ^ 1) * kBuf;
    const bool do_stage = (it + 1 < kIt);

    if (it + 2 < kIt) {
      #pragma unroll
      for (int jj = 0; jj < 4; ++jj)
        pfB[jj] = *(const float4*)(xg + (size_t)(mB + 8 * jj) * kD + (it + 2) * kBK + kc);
    }

    // ---- A for cluster0 (gc-local = kp): kh0 and kh1, 3 planes each
    const unsigned char* ra = rb + kp * kGS + aOct + aRow;
    short8 AH0 = *(const short8*)(ra);
    short8 AM0 = *(const short8*)(ra + kPS);
    short8 AL0 = *(const short8*)(ra + 2 * kPS);
    short8 AH1 = *(const short8*)(ra + 2 * kOS);
    short8 AM1 = *(const short8*)(ra + 2 * kOS + kPS);
    short8 AL1 = *(const short8*)(ra + 2 * kOS + 2 * kPS);

    // ---- B for cluster1 (g = it*4 + 2 + kp)
    short8 BnH0, BnM0, BnL0, BnH1, BnM1, BnL1;
    {
      const int g1 = it * 4 + 2 + kp;
      size_t b0 = bIdx(g1, 0), b1 = bIdx(g1, 1);
      BnH0 = *(const short8*)&g_B[b0];
      BnM0 = *(const short8*)&g_B[kPlaneU + b0];
      BnL0 = *(const short8*)&g_B[2 * kPlaneU + b0];
      BnH1 = *(const short8*)&g_B[b1];
      BnM1 = *(const short8*)&g_B[kPlaneU + b1];
      BnL1 = *(const short8*)&g_B[2 * kPlaneU + b1];
    }

    if (do_stage) {
      stage(pfA[0], sx[0], sxx[0], mB,     wb);
      stage(pfA[1], sx[1], sxx[1], mB + 8, wb);
    }

    // ---- cluster0 MFMAs: limb order (hh,hm,mh,mm,hl,lh) per kh, 2 chains
    __builtin_amdgcn_s_setprio(1);
    accA = __builtin_amdgcn_mfma_f32_32x32x16_bf16(AH0, BcH0, accA, 0, 0, 0);
    accB = __builtin_amdgcn_mfma_f32_32x32x16_bf16(AH1, BcH1, accB, 0, 0, 0);
    accA = __builtin_amdgcn_mfma_f32_32x32x16_bf16(AH0, BcM0, accA, 0, 0, 0);
    accB = __builtin_amdgcn_mfma_f32_32x32x16_bf16(AH1, BcM1, accB, 0, 0, 0);
    accA = __builtin_amdgcn_mfma_f32_32x32x16_bf16(AM0, BcH0, accA, 0, 0, 0);
    accB = __builtin_amdgcn_mfma_f32_32x32x16_bf16(AM1, BcH1, accB, 0, 0, 0);
    accA = __builtin_amdgcn_mfma_f32_32x32x16_bf16(AM0, BcM0, accA, 0, 0, 0);
    accB = __builtin_amdgcn_mfma_f32_32x32x16_bf16(AM1, BcM1, accB, 0, 0, 0);
    accA = __builtin_amdgcn_mfma_f32_32x32x16_bf16(AH0, BcL0, accA, 0, 0, 0);
    accB = __builtin_amdgcn_mfma_f32_32x32x16_bf16(AH1, BcL1, accB, 0, 0, 0);
    accA = __builtin_amdgcn_mfma_f32_32x32x16_bf16(AL0, BcH0, accA, 0, 0, 0);
    accB = __builtin_amdgcn_mfma_f32_32x32x16_bf16(AL1, BcH1, accB, 0, 0, 0);
    __builtin_amdgcn_s_setprio(0);

    // ---- A for cluster1 (gc-local = 2 + kp)
    const unsigned char* rc = rb + (2 + kp) * kGS + aOct + aRow;
    AH0 = *(const short8*)(rc);
    AM0 = *(const short8*)(rc + kPS);
    AL0 = *(const short8*)(rc + 2 * kPS);
    AH1 = *(const short8*)(rc + 2 * kOS);
    AM1 = *(const short8*)(rc + 2 * kOS + kPS);
    AL1 = *(const short8*)(rc + 2 * kOS + 2 * kPS);

    // ---- B for next iteration's cluster0 (wraps harmlessly at the end)
    short8 BfH0, BfM0, BfL0, BfH1, BfM1, BfL1;
    {
      const int gN = ((it + 1) * 4 + kp) & 63;
      size_t b0 = bIdx(gN, 0), b1 = bIdx(gN, 1);
      BfH0 = *(const short8*)&g_B[b0];
      BfM0 = *(const short8*)&g_B[kPlaneU + b0];
      BfL0 = *(const short8*)&g_B[2 * kPlaneU + b0];
      BfH1 = *(const short8*)&g_B[b1];
      BfM1 = *(const short8*)&g_B[kPlaneU + b1];
      BfL1 = *(const short8*)&g_B[2 * kPlaneU + b1];
    }

    if (do_stage) {
      stage(pfA[2], sx[2], sxx[2], mB + 16, wb);
      stage(pfA[3], sx[3], sxx[3], mB + 24, wb);
    }

    // ---- cluster1 MFMAs
    __builtin_amdgcn_s_setprio(1);
    accA = __builtin_amdgcn_mfma_f32_32x32x16_bf16(AH0, BnH0, accA, 0, 0, 0);
    accB = __builtin_amdgcn_mfma_f32_32x32x16_bf16(AH1, BnH1, accB, 0, 0, 0);
    accA = __builtin_amdgcn_mfma_f32_32x32x16_bf16(AH0, BnM0, accA, 0, 0, 0);
    accB = __builtin_amdgcn_mfma_f32_32x32x16_bf16(AH1, BnM1, accB, 0, 0, 0);
    accA = __builtin_amdgcn_mfma_f32_32x32x16_bf16(AM0, BnH0, accA, 0, 0, 0);
    accB = __builtin_amdgcn_mfma_f32_32x32x16_bf16(AM1, BnH1, accB, 0, 0, 0);
    accA = __builtin_amdgcn_mfma_f32_32x32x16_bf16(AM0, BnM0, accA, 0, 0, 0);
    accB = __builtin_amdgcn_mfma_f32_32x32x16_bf16(AM1, BnM1, accB, 0, 0, 0);
    accA = __builtin_amdgcn_mfma_f32_32x32x16_bf16(AH0, BnL0, accA, 0, 0, 0);
    accB = __builtin_amdgcn_mfma_f32_32x32x16_bf16(AH1, BnL1, accB, 0, 0, 0);
    accA = __builtin_amdgcn_mfma_f32_32x32x16_bf16(AL0, BnH0, accA, 0, 0, 0);
    accB = __builtin_amdgcn_mfma_f32_32x32x16_bf16(AL1, BnH1, accB, 0, 0, 0);
    __builtin_amdgcn_s_setprio(0);

    BcH0 = BfH0; BcM0 = BfM0; BcL0 = BfL0;
    BcH1 = BfH1; BcM1 = BfM1; BcL1 = BfL1;

    __syncthreads();
    if (it + 2 < kIt) {
      #pragma unroll
      for (int jj = 0; jj < 4; ++jj) pfA[jj] = pfB[jj];
    }
  }

  // LN stats: reduce within each 32-lane (same-token-slice) group
  #pragma unroll
  for (int jj = 0; jj < 4; ++jj) {
    float a = sx[jj], b = sxx[jj];
    #pragma unroll
    for (int off = 16; off >= 1; off >>= 1) {
      a += __shfl_xor(a, off, 64);
      b += __shfl_xor(b, off, 64);
    }
    if ((L & 31) == 0) {
      int m = mB + 8 * jj;
      sStats[m][0] = a;
      sStats[m][1] = b;
    }
  }

  // K-parity partial dots -> LDS plane kp
  // C layout (32x32): col = L&31, row = (i&3) + 8*(i>>2) + 4*(L>>5)
  #pragma unroll
  for (int i = 0; i < 16; ++i) {
    int row = (i & 3) + 8 * (i >> 2) + 4 * (L >> 5);
    sLogit[(kp * kM + row) * 68 + eg * 32 + (L & 31)] = accA[i] + accB[i];
  }
  __syncthreads();

  // epilogue: wave w -> tokens [8w, 8w+8), lane = expert
  const float Se  = ws[L];
  const float inv = ws[kE + L];
  #pragma unroll
  for (int tl = 0; tl < 8; ++tl) {
    int tk = w * 8 + tl;
    float mu   = sStats[tk][0] * (1.f / kD);
    float var  = sStats[tk][1] * (1.f / kD) - mu * mu;
    float rstd = rsqrtf(var + 1e-5f);
    float dot  = sLogit[tk * 68 + L] + sLogit[(kM + tk) * 68 + L];
    float logit = (dot - mu * Se) * rstd * inv * 0.125f;

    float v1 = logit; int i1 = L;
    #pragma unroll
    for (int off = 32; off >= 1; off >>= 1) {
      float ov = __shfl_xor(v1, off, 64);
      int   oi = __shfl_xor(i1, off, 64);
      if (ov > v1 || (ov == v1 && oi < i1)) { v1 = ov; i1 = oi; }
    }
    float ml = (L == i1) ? -3.402823466e38f : logit;
    float v2 = ml; int i2 = L;
    #pragma unroll
    for (int off = 32; off >= 1; off >>= 1) {
      float ov = __shfl_xor(v2, off, 64);
      int   oi = __shfl_xor(i2, off, 64);
      if (ov > v2 || (ov == v2 && oi < i2)) { v2 = ov; i2 = oi; }
    }
    if (L == 0) {
      int tg = tok0 + tk;
      float er = expf(v2 - v1);
      float r  = 1.f / (1.f + er);
      out_w[2 * tg]     = r;
      out_w[2 * tg + 1] = er * r;
      out_i[2 * tg]     = (float)i1;   // harness reads whole buffer as f32
      out_i[2 * tg + 1] = (float)i2;
    }
  }
}

extern "C" void kernel_launch(void* const* d_in, const int* in_sizes, int n_in,
                              void* d_out, int out_size, void* d_ws, size_t ws_size,
                              hipStream_t stream) {
  const float* x = (const float*)d_in[0];   // [4,4096,2048] fp32
  const float* p = (const float*)d_in[1];   // [64,2048] fp32
  float* ws = (float*)d_ws;                 // 128 floats
  const int T = in_sizes[0] / kD;           // 16384 tokens
  float* out_w = (float*)d_out;
  float* out_i = (float*)d_out + (size_t)T * 2;

  proto_prep<<<kE, 256, 0, stream>>>(p, ws);
  router_main<<<T / kM, 256, 0, stream>>>(x, ws, out_w, out_i);
}